// Round 5
// baseline (409.083 us; speedup 1.0000x reference)
//
#include <hip/hip_runtime.h>

typedef unsigned short u16;
typedef float f32x4 __attribute__((ext_vector_type(4)));
typedef __bf16 bf16x8 __attribute__((ext_vector_type(8)));

// ---------- bf16 helpers (RNE) ----------
__device__ __forceinline__ u16 f2bf(float f) {
    unsigned u = __float_as_uint(f);
    u += 0x7FFFu + ((u >> 16) & 1u);
    return (u16)(u >> 16);
}
__device__ __forceinline__ float b2f(u16 h) {
    return __uint_as_float(((unsigned)h) << 16);
}

// ---------- async global->LDS, 16B per lane, wave-uniform LDS base ----------
__device__ __forceinline__ void async16(const u16* g, u16* l) {
    __builtin_amdgcn_global_load_lds(
        (__attribute__((address_space(1))) void*)(u16*)g,
        (__attribute__((address_space(3))) void*)l,
        16, 0, 0);
}

#define T_TOK 4096
#define DIM   2048

// ---------- fused: W_in cast (blocks 0..8191) + LayerNorm (blocks 8192..12287) ----------
__global__ __launch_bounds__(256) void castln_kernel(const float* __restrict__ W_in,
                                                     u16* __restrict__ wb_in,
                                                     const float* __restrict__ x,
                                                     const float* __restrict__ g,
                                                     const float* __restrict__ b,
                                                     u16* __restrict__ o) {
    __shared__ float s1[4], s2[4];
    int blk = blockIdx.x, tid = threadIdx.x;
    if (blk < 8192) {               // cast path: 2,097,152 float4s
        int i = blk * 256 + tid;
        float4 f = ((const float4*)W_in)[i];
        ushort4 u;
        u.x = f2bf(f.x); u.y = f2bf(f.y); u.z = f2bf(f.z); u.w = f2bf(f.w);
        ((ushort4*)wb_in)[i] = u;
        return;
    }
    int t = blk - 8192;
    int wave = tid >> 6, lane = tid & 63;
    size_t base = (size_t)t * DIM;
    int d0 = tid * 8;
    float4 v0 = *(const float4*)(x + base + d0);
    float4 v1 = *(const float4*)(x + base + d0 + 4);
    float v[8] = {v0.x, v0.y, v0.z, v0.w, v1.x, v1.y, v1.z, v1.w};
    float s = 0.f;
#pragma unroll
    for (int j = 0; j < 8; ++j) s += v[j];
#pragma unroll
    for (int o2 = 32; o2; o2 >>= 1) s += __shfl_xor(s, o2);
    if (lane == 0) s1[wave] = s;
    __syncthreads();
    float mu = (s1[0] + s1[1] + s1[2] + s1[3]) * (1.f / DIM);
    float q = 0.f;
#pragma unroll
    for (int j = 0; j < 8; ++j) { float dd = v[j] - mu; q += dd * dd; }
#pragma unroll
    for (int o2 = 32; o2; o2 >>= 1) q += __shfl_xor(q, o2);
    if (lane == 0) s2[wave] = q;
    __syncthreads();
    float var = (s2[0] + s2[1] + s2[2] + s2[3]) * (1.f / DIM);
    float rs = rsqrtf(var + 1e-5f);
    float4 g0 = *(const float4*)(g + d0), g1 = *(const float4*)(g + d0 + 4);
    float4 b0 = *(const float4*)(b + d0), b1 = *(const float4*)(b + d0 + 4);
    float gv[8] = {g0.x, g0.y, g0.z, g0.w, g1.x, g1.y, g1.z, g1.w};
    float bv[8] = {b0.x, b0.y, b0.z, b0.w, b1.x, b1.y, b1.z, b1.w};
    ushort4 r0, r1;
    u16* rp0 = (u16*)&r0; u16* rp1 = (u16*)&r1;
#pragma unroll
    for (int j = 0; j < 4; ++j) {
        rp0[j] = f2bf((v[j] - mu) * rs * gv[j] + bv[j]);
        rp1[j] = f2bf((v[j + 4] - mu) * rs * gv[j + 4] + bv[j + 4]);
    }
    *(ushort4*)(o + base + d0) = r0;
    *(ushort4*)(o + base + d0 + 4) = r1;
}

// ---------- 4-range weight cast (W_dt, W_B, W_C, W_out in one launch) ----------
__global__ __launch_bounds__(256) void cast4_kernel(const float* __restrict__ s0, u16* __restrict__ d0, int n0,
                                                    const float* __restrict__ s1, u16* __restrict__ d1, int n1,
                                                    const float* __restrict__ s2, u16* __restrict__ d2, int n2,
                                                    const float* __restrict__ s3, u16* __restrict__ d3, int n3) {
    int j = blockIdx.x * 256 + threadIdx.x;
    const float* s; u16* d;
    if (j < n0) { s = s0; d = d0; }
    else {
        j -= n0;
        if (j < n1) { s = s1; d = d1; }
        else {
            j -= n1;
            if (j < n2) { s = s2; d = d2; }
            else { j -= n2; if (j >= n3) return; s = s3; d = d3; }
        }
    }
    float4 f = ((const float4*)s)[j];
    ushort4 u;
    u.x = f2bf(f.x); u.y = f2bf(f.y); u.z = f2bf(f.z); u.w = f2bf(f.w);
    ((ushort4*)d)[j] = u;
}

// ---------- unified 256x256 8-phase GEMM, 3 epilogues ----------
// ROUND-5 single change vs round-4 (80.5us, null on pin-removal): staging is
// now FINE-GRAINED -- one half-tile (2 global_load_lds/thread) issued in
// EVERY phase (m196: coarse burst staging vs per-phase interleave = -7..27%).
// WAR-derived schedule (iter i: buf0=tile 2i read p0-3, buf1=2i+1 read p4-7):
//   p0: A-h1->buf1@k1   p1: B-h0->buf1@k1   p2: B-h1->buf1@k1
//   p3: A-h0->buf0@kn  +vmcnt(2)            p4: A-h1->buf0@kn
//   p5: B-h0->buf0@kn   p6: B-h1->buf0@kn   p7: A-h0->buf1@kn1 +vmcnt(2)
// In-order vmcnt: at each wait exactly one phase's 2 loads remain -> vmcnt(2);
// every load has >=1 phase (~1400cy) cover > ~900cy HBM latency.
// DMA-vs-ds_read safety: each staged region's last ds_read drains at the
// previous phase's mid-phase lgkmcnt(0), sealed by that phase's end barrier.
// Phase body (validated rounds 3/4, identical perf with/without pins):
//   ds_reads; stage(2); s_barrier; lgkmcnt(0)[mem]; setprio1; 16 MFMA;
//   setprio0; [vmcnt(2)[mem]]; s_barrier
// EPI 0: split cols<2048 -> C0 (Xs bf16), >=2048 -> C1 (Z bf16)
// EPI 1: cols<2048 -> min(softplus(v+bias),1) bf16 -> C0 (dt);
//        2048..2079 -> raw dot bf16 -> C1 (dots, ld 32); >=2080 discarded.
// EPI 2: fp32 v + bias + resid -> C0
#define GBM 256
#define GBN 256
#define GBK 64

#define WAITV2 asm volatile("s_waitcnt vmcnt(2)" ::: "memory")

template <int EPI>
__global__ __launch_bounds__(512) void gemm256(const u16* __restrict__ A,
                                               const u16* __restrict__ W,
                                               const float* __restrict__ bias,
                                               const float* __restrict__ resid,
                                               void* __restrict__ C0,
                                               void* __restrict__ C1, int K) {
    __shared__ __align__(16) u16 lA[2][GBM * GBK];   // 64 KB
    __shared__ __align__(16) u16 lB[2][GBN * GBK];   // 64 KB
    const int tid = threadIdx.x;
    const int wv = tid >> 6, lane = tid & 63;
    const int quad = lane >> 4, l16 = lane & 15;
    const int wr = wv >> 2, wc = wv & 3;               // 2 x 4 wave grid
    const int tM = blockIdx.x * GBM, tN = blockIdx.y * GBN;

    // staging: 512 threads x 16B = 8 KB/round = 64 rows; 4 rounds per tile,
    // 2 rounds per half-tile (H=0: rows 0-127, H=1: rows 128-255).
    const int srow = tid >> 3;                          // 0..63
    const int swz = ((tid & 7) ^ (srow & 7)) * 8;       // pre-swizzled src chunk
    const u16* gA = A + (size_t)(tM + srow) * 2048 + swz;
    const u16* gW = W + (size_t)(tN + srow) * 2048 + swz;

#define STAGE_AH(BI, KC, H) do {                                              \
    _Pragma("unroll") for (int r_ = 2 * (H); r_ < 2 * (H) + 2; ++r_)          \
      async16(gA + (size_t)r_ * 64 * 2048 + (KC),                             \
              &lA[BI][(r_ * 64 + wv * 8) * GBK]);                             \
  } while (0)
#define STAGE_BH(BI, KC, H) do {                                              \
    _Pragma("unroll") for (int r_ = 2 * (H); r_ < 2 * (H) + 2; ++r_)          \
      async16(gW + (size_t)r_ * 64 * 2048 + (KC),                             \
              &lB[BI][(r_ * 64 + wv * 8) * GBK]);                             \
  } while (0)

    // ds_read offsets (elements): chunk h*4+quad of row R at slot ^(R&7).
    int aoff[2][4][2], boff[2][2][2];
#pragma unroll
    for (int qm = 0; qm < 2; ++qm)
#pragma unroll
        for (int mi = 0; mi < 4; ++mi)
#pragma unroll
            for (int h = 0; h < 2; ++h) {
                int row = wr * 128 + (qm * 4 + mi) * 16 + l16;
                aoff[qm][mi][h] = row * GBK + (((h * 4 + quad) ^ (l16 & 7)) * 8);
            }
#pragma unroll
    for (int qn = 0; qn < 2; ++qn)
#pragma unroll
        for (int ni = 0; ni < 2; ++ni)
#pragma unroll
            for (int h = 0; h < 2; ++h) {
                int row = wc * 64 + (qn * 2 + ni) * 16 + l16;
                boff[qn][ni][h] = row * GBK + (((h * 4 + quad) ^ (l16 & 7)) * 8);
            }

    f32x4 acc[8][4] = {};
    bf16x8 af[4][2];   // A frags persist across the two phases of a qm-half

#define PHASE(BI, QM, QN, LOADA, STAGE_STMT, WAIT_STMT) do {                  \
    if (LOADA) {                                                              \
      _Pragma("unroll") for (int mi_ = 0; mi_ < 4; ++mi_)                     \
        _Pragma("unroll") for (int h_ = 0; h_ < 2; ++h_)                      \
          af[mi_][h_] = *(const bf16x8*)&lA[BI][aoff[QM][mi_][h_]];           \
    }                                                                         \
    bf16x8 bfr_[2][2];                                                        \
    _Pragma("unroll") for (int ni_ = 0; ni_ < 2; ++ni_)                       \
      _Pragma("unroll") for (int h_ = 0; h_ < 2; ++h_)                        \
        bfr_[ni_][h_] = *(const bf16x8*)&lB[BI][boff[QN][ni_][h_]];           \
    STAGE_STMT;                                                               \
    __builtin_amdgcn_s_barrier();                                             \
    asm volatile("s_waitcnt lgkmcnt(0)" ::: "memory");                        \
    __builtin_amdgcn_s_setprio(1);                                            \
    _Pragma("unroll") for (int mi_ = 0; mi_ < 4; ++mi_)                       \
      _Pragma("unroll") for (int ni_ = 0; ni_ < 2; ++ni_)                     \
        _Pragma("unroll") for (int h_ = 0; h_ < 2; ++h_)                      \
          acc[QM * 4 + mi_][QN * 2 + ni_] =                                   \
              __builtin_amdgcn_mfma_f32_16x16x32_bf16(                        \
                  af[mi_][h_], bfr_[ni_][h_],                                 \
                  acc[QM * 4 + mi_][QN * 2 + ni_], 0, 0, 0);                  \
    __builtin_amdgcn_s_setprio(0);                                            \
    WAIT_STMT;                                                                \
    __builtin_amdgcn_s_barrier();                                             \
  } while (0)

    // prologue: tile0 (A+B, 8 loads) + tile1 A-h0 (2 loads); wait tile0 landed
    // (A1h0's 2 loads stay in flight) -- uniform with steady-state schedule.
    STAGE_AH(0, 0, 0);
    STAGE_AH(0, 0, 1);
    STAGE_BH(0, 0, 0);
    STAGE_BH(0, 0, 1);
    STAGE_AH(1, 64, 0);
    WAITV2;
    __builtin_amdgcn_s_barrier();

    const int NIT = K >> 7;                 // 2 K-tiles per iteration
    for (int it = 0; it < NIT; ++it) {
        const int k1 = it * 128 + 64;       // buf1 tile (read p4-7)
        int kn = it * 128 + 128;            // next buf0 tile
        if (kn > K - 64) kn = K - 64;       // last iter: clamped, harmless
        int kn1 = it * 128 + 192;           // next buf1 tile
        if (kn1 > K - 64) kn1 = K - 64;

        PHASE(0, 0, 0, 1, STAGE_AH(1, k1, 1),  (void)0);   // p0
        PHASE(0, 0, 1, 0, STAGE_BH(1, k1, 0),  (void)0);   // p1
        PHASE(0, 1, 0, 1, STAGE_BH(1, k1, 1),  (void)0);   // p2
        PHASE(0, 1, 1, 0, STAGE_AH(0, kn, 0),  WAITV2);    // p3: buf1 ready
        PHASE(1, 0, 0, 1, STAGE_AH(0, kn, 1),  (void)0);   // p4
        PHASE(1, 0, 1, 0, STAGE_BH(0, kn, 0),  (void)0);   // p5
        PHASE(1, 1, 0, 1, STAGE_BH(0, kn, 1),  (void)0);   // p6
        PHASE(1, 1, 1, 0, STAGE_AH(1, kn1, 0), WAITV2);    // p7: buf0 ready
    }

    asm volatile("s_waitcnt vmcnt(0)" ::: "memory");   // drain DMA before exit

    // D frag layout: row = quad*4+r, col = l16.
#pragma unroll
    for (int mi = 0; mi < 8; ++mi) {
#pragma unroll
        for (int ni = 0; ni < 4; ++ni) {
            int col = tN + wc * 64 + ni * 16 + l16;
            if constexpr (EPI == 0) {
                const bool isb_z = (tN >= 2048);   // uniform per block (GBN=256)
                u16* dst = isb_z ? (u16*)C1 : (u16*)C0;
                float bv = bias[col];
                int ocol = isb_z ? (col - 2048) : col;
#pragma unroll
                for (int r = 0; r < 4; ++r) {
                    int row = tM + wr * 128 + mi * 16 + quad * 4 + r;
                    dst[(size_t)row * 2048 + ocol] = f2bf(acc[mi][ni][r] + bv);
                }
            } else if constexpr (EPI == 1) {
                if (col < 2048) {
                    float bv = bias[col];
#pragma unroll
                    for (int r = 0; r < 4; ++r) {
                        int row = tM + wr * 128 + mi * 16 + quad * 4 + r;
                        float v = acc[mi][ni][r] + bv;
                        // min(softplus(v),1): v > ln(e-1) -> 1
                        float sp = (v > 0.5413f) ? 1.0f
                                                 : __logf(1.0f + __expf(v));
                        ((u16*)C0)[(size_t)row * 2048 + col] = f2bf(sp);
                    }
                } else if (col < 2080) {
#pragma unroll
                    for (int r = 0; r < 4; ++r) {
                        int row = tM + wr * 128 + mi * 16 + quad * 4 + r;
                        ((u16*)C1)[(size_t)row * 32 + (col - 2048)] =
                            f2bf(acc[mi][ni][r]);
                    }
                }
            } else {
                float bv = bias[col];
#pragma unroll
                for (int r = 0; r < 4; ++r) {
                    int row = tM + wr * 128 + mi * 16 + quad * 4 + r;
                    size_t idx = (size_t)row * 2048 + col;
                    ((float*)C0)[idx] = acc[mi][ni][r] + bv + resid[idx];
                }
            }
        }
    }
#undef PHASE
#undef STAGE_AH
#undef STAGE_BH
}

// ---------- fused P + SSM + gate (split xs/z inputs) ----------
__global__ __launch_bounds__(256) void ssm_gate_kernel(const u16* __restrict__ dtb,
                                                       const u16* __restrict__ xsb,
                                                       const u16* __restrict__ zb,
                                                       const float* __restrict__ A,
                                                       const u16* __restrict__ dots,
                                                       const float* __restrict__ bB,
                                                       const float* __restrict__ bC,
                                                       u16* __restrict__ gated) {
    __shared__ float Pl[16];
    int t = blockIdx.x, tid = threadIdx.x;
    if (tid < 16) {
        float Bv = b2f(dots[(size_t)t * 32 + tid]) + bB[tid];
        float Cv = b2f(dots[(size_t)t * 32 + 16 + tid]) + bC[tid];
        Pl[tid] = Bv * Cv;
    }
    __syncthreads();
    size_t dbase = (size_t)t * DIM;
    int d0 = tid * 8;
    ushort4 dth[2], xsh[2], zh[2];
    dth[0] = *(const ushort4*)(dtb + dbase + d0);
    dth[1] = *(const ushort4*)(dtb + dbase + d0 + 4);
    xsh[0] = *(const ushort4*)(xsb + dbase + d0);
    xsh[1] = *(const ushort4*)(xsb + dbase + d0 + 4);
    zh[0]  = *(const ushort4*)(zb + dbase + d0);
    zh[1]  = *(const ushort4*)(zb + dbase + d0 + 4);
    float dtv[8], xsv[8], zv[8];
#pragma unroll
    for (int h = 0; h < 2; ++h) {
        const u16* dp = (const u16*)&dth[h];
        const u16* xp = (const u16*)&xsh[h];
        const u16* zp = (const u16*)&zh[h];
#pragma unroll
        for (int j = 0; j < 4; ++j) {
            dtv[h * 4 + j] = b2f(dp[j]);
            xsv[h * 4 + j] = b2f(xp[j]);
            zv[h * 4 + j]  = b2f(zp[j]);
        }
    }
    float s[8] = {};
#pragma unroll
    for (int n = 0; n < 16; ++n) {
        float4 a0 = *(const float4*)(A + n * DIM + d0);
        float4 a1 = *(const float4*)(A + n * DIM + d0 + 4);
        float pn = Pl[n];
        float av[8] = {a0.x, a0.y, a0.z, a0.w, a1.x, a1.y, a1.z, a1.w};
#pragma unroll
        for (int j = 0; j < 8; ++j) s[j] += pn * __expf(av[j] * dtv[j]);
    }
    ushort4 r0, r1;
    u16* rp0 = (u16*)&r0; u16* rp1 = (u16*)&r1;
#pragma unroll
    for (int j = 0; j < 8; ++j) {
        float y = s[j] * xsv[j];
        float sz = zv[j] * (1.0f / (1.0f + __expf(-zv[j])));
        u16 hv = f2bf(y * sz);
        if (j < 4) rp0[j] = hv; else rp1[j - 4] = hv;
    }
    *(ushort4*)(gated + dbase + d0) = r0;
    *(ushort4*)(gated + dbase + d0 + 4) = r1;
}

// ---------- launch ----------
// ws layout (84.15 MB peak):
//   R0 [0, 16.78M):       wb_in bf16 -> after gemm256<0>: wb_out bf16 [0, 8.39M)
//   R1 [16.78M, 33.55M):  xnb bf16 -> wb_dt bf16 2304x2048 (9.44M; rows
//                         2080-2303 uninit, outputs discarded) -> gated bf16
//   R2 [33.55M, 50.33M):  xsb bf16 (T x D)
//   R3 [50.33M, 67.11M):  zb  bf16 (T x D)
//   R4 [67.11M, 83.89M):  dtb bf16 (T x D)
//   R5 [83.89M, 84.15M):  dots bf16 (T x 32)
extern "C" void kernel_launch(void* const* d_in, const int* in_sizes, int n_in,
                              void* d_out, int out_size, void* d_ws, size_t ws_size,
                              hipStream_t stream) {
    const float* x      = (const float*)d_in[0];
    const float* ln_g   = (const float*)d_in[1];
    const float* ln_b   = (const float*)d_in[2];
    const float* W_in   = (const float*)d_in[3];
    const float* b_in   = (const float*)d_in[4];
    const float* stateA = (const float*)d_in[5];
    const float* W_B    = (const float*)d_in[6];
    const float* b_B    = (const float*)d_in[7];
    const float* W_C    = (const float*)d_in[8];
    const float* b_C    = (const float*)d_in[9];
    const float* W_dt   = (const float*)d_in[10];
    const float* b_dt   = (const float*)d_in[11];
    const float* W_out  = (const float*)d_in[12];
    const float* b_out  = (const float*)d_in[13];

    char* ws = (char*)d_ws;
    u16*   wb_in  = (u16*)(ws);                     // R0
    u16*   wb_out = (u16*)(ws);                     // R0 reuse (8.4 MB)
    u16*   xnb    = (u16*)(ws + 16777216);          // R1
    u16*   wb_dt  = (u16*)(ws + 16777216);          // R1 reuse: 2304 x 2048
    u16*   gated  = (u16*)(ws + 16777216);          // R1 reuse: T x D
    u16*   xsb    = (u16*)(ws + 33554432);          // R2: T x D
    u16*   zb     = (u16*)(ws + 50331648);          // R3: T x D
    u16*   dtb    = (u16*)(ws + 67108864);          // R4: T x D
    u16*   dotsb  = (u16*)(ws + 83886080);          // R5: T x 32

    // 1. fused W_in cast + LN(x)
    castln_kernel<<<12288, 256, 0, stream>>>(W_in, wb_in, x, ln_g, ln_b, xnb);
    // 2. xz = xn @ W_in^T + b_in -> xsb | zb   (256^2 8-phase, 256 blocks)
    gemm256<0><<<dim3(16, 16), 512, 0, stream>>>(xnb, wb_in, b_in, nullptr,
                                                 xsb, zb, 2048);
    // 3. cast W_dt -> wb_dt rows 0..2047, W_B -> 2048..2063, W_C -> 2064..2079,
    //    W_out -> wb_out (R0). Rows 2080..2303 uninit; those cols discarded.
    cast4_kernel<<<8256, 256, 0, stream>>>(
        W_dt, wb_dt, 1048576,
        W_B,  wb_dt + (size_t)2048 * 2048, 8192,
        W_C,  wb_dt + (size_t)2064 * 2048, 8192,
        W_out, wb_out, 1048576);
    // 4. dt GEMM + BC dots: N padded to 2304 (9 tiles), 144 blocks
    gemm256<1><<<dim3(16, 9), 512, 0, stream>>>(xsb, wb_dt, b_dt, nullptr,
                                                dtb, dotsb, 2048);
    // 5. fused P + SSM + gate (gated overwrites R1; wb_dt dead)
    ssm_gate_kernel<<<T_TOK, 256, 0, stream>>>(dtb, xsb, zb, stateA, dotsb,
                                               b_B, b_C, gated);
    // 6. out = gated @ W_out^T + b_out + x, 128 blocks
    gemm256<2><<<dim3(16, 8), 512, 0, stream>>>(gated, wb_out, b_out, x,
                                                (float*)d_out, nullptr, 2048);
}

// Round 6
// 398.737 us; speedup vs baseline: 1.0259x; 1.0259x over previous
//
#include <hip/hip_runtime.h>

typedef unsigned short u16;
typedef float f32x4 __attribute__((ext_vector_type(4)));
typedef __bf16 bf16x8 __attribute__((ext_vector_type(8)));

// ---------- bf16 helpers (RNE) ----------
__device__ __forceinline__ u16 f2bf(float f) {
    unsigned u = __float_as_uint(f);
    u += 0x7FFFu + ((u >> 16) & 1u);
    return (u16)(u >> 16);
}
__device__ __forceinline__ float b2f(u16 h) {
    return __uint_as_float(((unsigned)h) << 16);
}

// ---------- async global->LDS, 16B per lane, wave-uniform LDS base ----------
__device__ __forceinline__ void async16(const u16* g, u16* l) {
    __builtin_amdgcn_global_load_lds(
        (__attribute__((address_space(1))) void*)(u16*)g,
        (__attribute__((address_space(3))) void*)l,
        16, 0, 0);
}

#define T_TOK 4096
#define DIM   2048

// ---------- fused: W_in cast (blocks 0..8191) + LayerNorm (blocks 8192..12287) ----------
__global__ __launch_bounds__(256) void castln_kernel(const float* __restrict__ W_in,
                                                     u16* __restrict__ wb_in,
                                                     const float* __restrict__ x,
                                                     const float* __restrict__ g,
                                                     const float* __restrict__ b,
                                                     u16* __restrict__ o) {
    __shared__ float s1[4], s2[4];
    int blk = blockIdx.x, tid = threadIdx.x;
    if (blk < 8192) {               // cast path: 2,097,152 float4s
        int i = blk * 256 + tid;
        float4 f = ((const float4*)W_in)[i];
        ushort4 u;
        u.x = f2bf(f.x); u.y = f2bf(f.y); u.z = f2bf(f.z); u.w = f2bf(f.w);
        ((ushort4*)wb_in)[i] = u;
        return;
    }
    int t = blk - 8192;
    int wave = tid >> 6, lane = tid & 63;
    size_t base = (size_t)t * DIM;
    int d0 = tid * 8;
    float4 v0 = *(const float4*)(x + base + d0);
    float4 v1 = *(const float4*)(x + base + d0 + 4);
    float v[8] = {v0.x, v0.y, v0.z, v0.w, v1.x, v1.y, v1.z, v1.w};
    float s = 0.f;
#pragma unroll
    for (int j = 0; j < 8; ++j) s += v[j];
#pragma unroll
    for (int o2 = 32; o2; o2 >>= 1) s += __shfl_xor(s, o2);
    if (lane == 0) s1[wave] = s;
    __syncthreads();
    float mu = (s1[0] + s1[1] + s1[2] + s1[3]) * (1.f / DIM);
    float q = 0.f;
#pragma unroll
    for (int j = 0; j < 8; ++j) { float dd = v[j] - mu; q += dd * dd; }
#pragma unroll
    for (int o2 = 32; o2; o2 >>= 1) q += __shfl_xor(q, o2);
    if (lane == 0) s2[wave] = q;
    __syncthreads();
    float var = (s2[0] + s2[1] + s2[2] + s2[3]) * (1.f / DIM);
    float rs = rsqrtf(var + 1e-5f);
    float4 g0 = *(const float4*)(g + d0), g1 = *(const float4*)(g + d0 + 4);
    float4 b0 = *(const float4*)(b + d0), b1 = *(const float4*)(b + d0 + 4);
    float gv[8] = {g0.x, g0.y, g0.z, g0.w, g1.x, g1.y, g1.z, g1.w};
    float bv[8] = {b0.x, b0.y, b0.z, b0.w, b1.x, b1.y, b1.z, b1.w};
    ushort4 r0, r1;
    u16* rp0 = (u16*)&r0; u16* rp1 = (u16*)&r1;
#pragma unroll
    for (int j = 0; j < 4; ++j) {
        rp0[j] = f2bf((v[j] - mu) * rs * gv[j] + bv[j]);
        rp1[j] = f2bf((v[j + 4] - mu) * rs * gv[j + 4] + bv[j + 4]);
    }
    *(ushort4*)(o + base + d0) = r0;
    *(ushort4*)(o + base + d0 + 4) = r1;
}

// ---------- 4-range weight cast (W_dt, W_B, W_C, W_out in one launch) ----------
__global__ __launch_bounds__(256) void cast4_kernel(const float* __restrict__ s0, u16* __restrict__ d0, int n0,
                                                    const float* __restrict__ s1, u16* __restrict__ d1, int n1,
                                                    const float* __restrict__ s2, u16* __restrict__ d2, int n2,
                                                    const float* __restrict__ s3, u16* __restrict__ d3, int n3) {
    int j = blockIdx.x * 256 + threadIdx.x;
    const float* s; u16* d;
    if (j < n0) { s = s0; d = d0; }
    else {
        j -= n0;
        if (j < n1) { s = s1; d = d1; }
        else {
            j -= n1;
            if (j < n2) { s = s2; d = d2; }
            else { j -= n2; if (j >= n3) return; s = s3; d = d3; }
        }
    }
    float4 f = ((const float4*)s)[j];
    ushort4 u;
    u.x = f2bf(f.x); u.y = f2bf(f.y); u.z = f2bf(f.z); u.w = f2bf(f.w);
    ((ushort4*)d)[j] = u;
}

// ---------- unified 256x256 8-phase GEMM, 3 epilogues ----------
// ROUND-6 single change vs round-5 (79.9us, null): ONE barrier per phase.
// Deleted the mid-phase {s_barrier; lgkmcnt(0)} -- it forced strict lockstep:
// all 8 waves issue 64KB of ds_read in the same window (LDS port ~770cy at
// 85B/cyc, NO MFMA running), then all do MFMA (port idle). Reads and MFMA
// were serialized by construction: 770+512+skew ~= the measured 1445cy/phase.
// With one barrier, waves slip within a phase: one wave's ds_reads are served
// under another wave's MFMAs (separate pipes); setprio gets role-diversity.
// Correctness: MFMA operand readiness is register-dep-tracked (compiler emits
// fine-grained lgkmcnt per consumer); all reads are consumed by this phase's
// MFMAs, so they drain before the end-barrier -> one barrier between last
// read of a region (phase p-1) and the DMA stage overwriting it (phase p) is
// sufficient WAR protection. Stage confirmation unchanged: vmcnt(2)[mem] at
// p3/p7 + end barrier; memory clobbers stop reads crossing the waits.
// Stage schedule per iter i (buf0=tile 2i read p0-3, buf1=2i+1 read p4-7):
//   p0: A-h1->buf1@k1   p1: B-h0->buf1@k1   p2: B-h1->buf1@k1
//   p3: A-h0->buf0@kn  +vmcnt(2)            p4: A-h1->buf0@kn
//   p5: B-h0->buf0@kn   p6: B-h1->buf0@kn   p7: A-h0->buf1@kn1 +vmcnt(2)
// Phase body: ds_reads; stage(2); setprio1; 16 MFMA; setprio0; [vmcnt(2)];
//             s_barrier
// EPI 0: split cols<2048 -> C0 (Xs bf16), >=2048 -> C1 (Z bf16)
// EPI 1: cols<2048 -> min(softplus(v+bias),1) bf16 -> C0 (dt);
//        2048..2079 -> raw dot bf16 -> C1 (dots, ld 32); >=2080 discarded.
// EPI 2: fp32 v + bias + resid -> C0
#define GBM 256
#define GBN 256
#define GBK 64

#define WAITV2 asm volatile("s_waitcnt vmcnt(2)" ::: "memory")

template <int EPI>
__global__ __launch_bounds__(512) void gemm256(const u16* __restrict__ A,
                                               const u16* __restrict__ W,
                                               const float* __restrict__ bias,
                                               const float* __restrict__ resid,
                                               void* __restrict__ C0,
                                               void* __restrict__ C1, int K) {
    __shared__ __align__(16) u16 lA[2][GBM * GBK];   // 64 KB
    __shared__ __align__(16) u16 lB[2][GBN * GBK];   // 64 KB
    const int tid = threadIdx.x;
    const int wv = tid >> 6, lane = tid & 63;
    const int quad = lane >> 4, l16 = lane & 15;
    const int wr = wv >> 2, wc = wv & 3;               // 2 x 4 wave grid
    const int tM = blockIdx.x * GBM, tN = blockIdx.y * GBN;

    // staging: 512 threads x 16B = 8 KB/round = 64 rows; 4 rounds per tile,
    // 2 rounds per half-tile (H=0: rows 0-127, H=1: rows 128-255).
    const int srow = tid >> 3;                          // 0..63
    const int swz = ((tid & 7) ^ (srow & 7)) * 8;       // pre-swizzled src chunk
    const u16* gA = A + (size_t)(tM + srow) * 2048 + swz;
    const u16* gW = W + (size_t)(tN + srow) * 2048 + swz;

#define STAGE_AH(BI, KC, H) do {                                              \
    _Pragma("unroll") for (int r_ = 2 * (H); r_ < 2 * (H) + 2; ++r_)          \
      async16(gA + (size_t)r_ * 64 * 2048 + (KC),                             \
              &lA[BI][(r_ * 64 + wv * 8) * GBK]);                             \
  } while (0)
#define STAGE_BH(BI, KC, H) do {                                              \
    _Pragma("unroll") for (int r_ = 2 * (H); r_ < 2 * (H) + 2; ++r_)          \
      async16(gW + (size_t)r_ * 64 * 2048 + (KC),                             \
              &lB[BI][(r_ * 64 + wv * 8) * GBK]);                             \
  } while (0)

    // ds_read offsets (elements): chunk h*4+quad of row R at slot ^(R&7).
    int aoff[2][4][2], boff[2][2][2];
#pragma unroll
    for (int qm = 0; qm < 2; ++qm)
#pragma unroll
        for (int mi = 0; mi < 4; ++mi)
#pragma unroll
            for (int h = 0; h < 2; ++h) {
                int row = wr * 128 + (qm * 4 + mi) * 16 + l16;
                aoff[qm][mi][h] = row * GBK + (((h * 4 + quad) ^ (l16 & 7)) * 8);
            }
#pragma unroll
    for (int qn = 0; qn < 2; ++qn)
#pragma unroll
        for (int ni = 0; ni < 2; ++ni)
#pragma unroll
            for (int h = 0; h < 2; ++h) {
                int row = wc * 64 + (qn * 2 + ni) * 16 + l16;
                boff[qn][ni][h] = row * GBK + (((h * 4 + quad) ^ (l16 & 7)) * 8);
            }

    f32x4 acc[8][4] = {};
    bf16x8 af[4][2];   // A frags persist across the two phases of a qm-half

#define PHASE(BI, QM, QN, LOADA, STAGE_STMT, WAIT_STMT) do {                  \
    if (LOADA) {                                                              \
      _Pragma("unroll") for (int mi_ = 0; mi_ < 4; ++mi_)                     \
        _Pragma("unroll") for (int h_ = 0; h_ < 2; ++h_)                      \
          af[mi_][h_] = *(const bf16x8*)&lA[BI][aoff[QM][mi_][h_]];           \
    }                                                                         \
    bf16x8 bfr_[2][2];                                                        \
    _Pragma("unroll") for (int ni_ = 0; ni_ < 2; ++ni_)                       \
      _Pragma("unroll") for (int h_ = 0; h_ < 2; ++h_)                        \
        bfr_[ni_][h_] = *(const bf16x8*)&lB[BI][boff[QN][ni_][h_]];           \
    STAGE_STMT;                                                               \
    __builtin_amdgcn_s_setprio(1);                                            \
    _Pragma("unroll") for (int mi_ = 0; mi_ < 4; ++mi_)                       \
      _Pragma("unroll") for (int ni_ = 0; ni_ < 2; ++ni_)                     \
        _Pragma("unroll") for (int h_ = 0; h_ < 2; ++h_)                      \
          acc[QM * 4 + mi_][QN * 2 + ni_] =                                   \
              __builtin_amdgcn_mfma_f32_16x16x32_bf16(                        \
                  af[mi_][h_], bfr_[ni_][h_],                                 \
                  acc[QM * 4 + mi_][QN * 2 + ni_], 0, 0, 0);                  \
    __builtin_amdgcn_s_setprio(0);                                            \
    WAIT_STMT;                                                                \
    __builtin_amdgcn_s_barrier();                                             \
  } while (0)

    // prologue: tile0 (A+B, 8 loads) + tile1 A-h0 (2 loads); wait tile0 landed
    // (A1h0's 2 loads stay in flight) -- uniform with steady-state schedule.
    STAGE_AH(0, 0, 0);
    STAGE_AH(0, 0, 1);
    STAGE_BH(0, 0, 0);
    STAGE_BH(0, 0, 1);
    STAGE_AH(1, 64, 0);
    WAITV2;
    __builtin_amdgcn_s_barrier();

    const int NIT = K >> 7;                 // 2 K-tiles per iteration
    for (int it = 0; it < NIT; ++it) {
        const int k1 = it * 128 + 64;       // buf1 tile (read p4-7)
        int kn = it * 128 + 128;            // next buf0 tile
        if (kn > K - 64) kn = K - 64;       // last iter: clamped, harmless
        int kn1 = it * 128 + 192;           // next buf1 tile
        if (kn1 > K - 64) kn1 = K - 64;

        PHASE(0, 0, 0, 1, STAGE_AH(1, k1, 1),  (void)0);   // p0
        PHASE(0, 0, 1, 0, STAGE_BH(1, k1, 0),  (void)0);   // p1
        PHASE(0, 1, 0, 1, STAGE_BH(1, k1, 1),  (void)0);   // p2
        PHASE(0, 1, 1, 0, STAGE_AH(0, kn, 0),  WAITV2);    // p3: buf1 ready
        PHASE(1, 0, 0, 1, STAGE_AH(0, kn, 1),  (void)0);   // p4
        PHASE(1, 0, 1, 0, STAGE_BH(0, kn, 0),  (void)0);   // p5
        PHASE(1, 1, 0, 1, STAGE_BH(0, kn, 1),  (void)0);   // p6
        PHASE(1, 1, 1, 0, STAGE_AH(1, kn1, 0), WAITV2);    // p7: buf0 ready
    }

    asm volatile("s_waitcnt vmcnt(0)" ::: "memory");   // drain DMA before exit

    // D frag layout: row = quad*4+r, col = l16.
#pragma unroll
    for (int mi = 0; mi < 8; ++mi) {
#pragma unroll
        for (int ni = 0; ni < 4; ++ni) {
            int col = tN + wc * 64 + ni * 16 + l16;
            if constexpr (EPI == 0) {
                const bool isb_z = (tN >= 2048);   // uniform per block (GBN=256)
                u16* dst = isb_z ? (u16*)C1 : (u16*)C0;
                float bv = bias[col];
                int ocol = isb_z ? (col - 2048) : col;
#pragma unroll
                for (int r = 0; r < 4; ++r) {
                    int row = tM + wr * 128 + mi * 16 + quad * 4 + r;
                    dst[(size_t)row * 2048 + ocol] = f2bf(acc[mi][ni][r] + bv);
                }
            } else if constexpr (EPI == 1) {
                if (col < 2048) {
                    float bv = bias[col];
#pragma unroll
                    for (int r = 0; r < 4; ++r) {
                        int row = tM + wr * 128 + mi * 16 + quad * 4 + r;
                        float v = acc[mi][ni][r] + bv;
                        // min(softplus(v),1): v > ln(e-1) -> 1
                        float sp = (v > 0.5413f) ? 1.0f
                                                 : __logf(1.0f + __expf(v));
                        ((u16*)C0)[(size_t)row * 2048 + col] = f2bf(sp);
                    }
                } else if (col < 2080) {
#pragma unroll
                    for (int r = 0; r < 4; ++r) {
                        int row = tM + wr * 128 + mi * 16 + quad * 4 + r;
                        ((u16*)C1)[(size_t)row * 32 + (col - 2048)] =
                            f2bf(acc[mi][ni][r]);
                    }
                }
            } else {
                float bv = bias[col];
#pragma unroll
                for (int r = 0; r < 4; ++r) {
                    int row = tM + wr * 128 + mi * 16 + quad * 4 + r;
                    size_t idx = (size_t)row * 2048 + col;
                    ((float*)C0)[idx] = acc[mi][ni][r] + bv + resid[idx];
                }
            }
        }
    }
#undef PHASE
#undef STAGE_AH
#undef STAGE_BH
}

// ---------- fused P + SSM + gate (split xs/z inputs) ----------
__global__ __launch_bounds__(256) void ssm_gate_kernel(const u16* __restrict__ dtb,
                                                       const u16* __restrict__ xsb,
                                                       const u16* __restrict__ zb,
                                                       const float* __restrict__ A,
                                                       const u16* __restrict__ dots,
                                                       const float* __restrict__ bB,
                                                       const float* __restrict__ bC,
                                                       u16* __restrict__ gated) {
    __shared__ float Pl[16];
    int t = blockIdx.x, tid = threadIdx.x;
    if (tid < 16) {
        float Bv = b2f(dots[(size_t)t * 32 + tid]) + bB[tid];
        float Cv = b2f(dots[(size_t)t * 32 + 16 + tid]) + bC[tid];
        Pl[tid] = Bv * Cv;
    }
    __syncthreads();
    size_t dbase = (size_t)t * DIM;
    int d0 = tid * 8;
    ushort4 dth[2], xsh[2], zh[2];
    dth[0] = *(const ushort4*)(dtb + dbase + d0);
    dth[1] = *(const ushort4*)(dtb + dbase + d0 + 4);
    xsh[0] = *(const ushort4*)(xsb + dbase + d0);
    xsh[1] = *(const ushort4*)(xsb + dbase + d0 + 4);
    zh[0]  = *(const ushort4*)(zb + dbase + d0);
    zh[1]  = *(const ushort4*)(zb + dbase + d0 + 4);
    float dtv[8], xsv[8], zv[8];
#pragma unroll
    for (int h = 0; h < 2; ++h) {
        const u16* dp = (const u16*)&dth[h];
        const u16* xp = (const u16*)&xsh[h];
        const u16* zp = (const u16*)&zh[h];
#pragma unroll
        for (int j = 0; j < 4; ++j) {
            dtv[h * 4 + j] = b2f(dp[j]);
            xsv[h * 4 + j] = b2f(xp[j]);
            zv[h * 4 + j]  = b2f(zp[j]);
        }
    }
    float s[8] = {};
#pragma unroll
    for (int n = 0; n < 16; ++n) {
        float4 a0 = *(const float4*)(A + n * DIM + d0);
        float4 a1 = *(const float4*)(A + n * DIM + d0 + 4);
        float pn = Pl[n];
        float av[8] = {a0.x, a0.y, a0.z, a0.w, a1.x, a1.y, a1.z, a1.w};
#pragma unroll
        for (int j = 0; j < 8; ++j) s[j] += pn * __expf(av[j] * dtv[j]);
    }
    ushort4 r0, r1;
    u16* rp0 = (u16*)&r0; u16* rp1 = (u16*)&r1;
#pragma unroll
    for (int j = 0; j < 8; ++j) {
        float y = s[j] * xsv[j];
        float sz = zv[j] * (1.0f / (1.0f + __expf(-zv[j])));
        u16 hv = f2bf(y * sz);
        if (j < 4) rp0[j] = hv; else rp1[j - 4] = hv;
    }
    *(ushort4*)(gated + dbase + d0) = r0;
    *(ushort4*)(gated + dbase + d0 + 4) = r1;
}

// ---------- launch ----------
// ws layout (84.15 MB peak):
//   R0 [0, 16.78M):       wb_in bf16 -> after gemm256<0>: wb_out bf16 [0, 8.39M)
//   R1 [16.78M, 33.55M):  xnb bf16 -> wb_dt bf16 2304x2048 (9.44M; rows
//                         2080-2303 uninit, outputs discarded) -> gated bf16
//   R2 [33.55M, 50.33M):  xsb bf16 (T x D)
//   R3 [50.33M, 67.11M):  zb  bf16 (T x D)
//   R4 [67.11M, 83.89M):  dtb bf16 (T x D)
//   R5 [83.89M, 84.15M):  dots bf16 (T x 32)
extern "C" void kernel_launch(void* const* d_in, const int* in_sizes, int n_in,
                              void* d_out, int out_size, void* d_ws, size_t ws_size,
                              hipStream_t stream) {
    const float* x      = (const float*)d_in[0];
    const float* ln_g   = (const float*)d_in[1];
    const float* ln_b   = (const float*)d_in[2];
    const float* W_in   = (const float*)d_in[3];
    const float* b_in   = (const float*)d_in[4];
    const float* stateA = (const float*)d_in[5];
    const float* W_B    = (const float*)d_in[6];
    const float* b_B    = (const float*)d_in[7];
    const float* W_C    = (const float*)d_in[8];
    const float* b_C    = (const float*)d_in[9];
    const float* W_dt   = (const float*)d_in[10];
    const float* b_dt   = (const float*)d_in[11];
    const float* W_out  = (const float*)d_in[12];
    const float* b_out  = (const float*)d_in[13];

    char* ws = (char*)d_ws;
    u16*   wb_in  = (u16*)(ws);                     // R0
    u16*   wb_out = (u16*)(ws);                     // R0 reuse (8.4 MB)
    u16*   xnb    = (u16*)(ws + 16777216);          // R1
    u16*   wb_dt  = (u16*)(ws + 16777216);          // R1 reuse: 2304 x 2048
    u16*   gated  = (u16*)(ws + 16777216);          // R1 reuse: T x D
    u16*   xsb    = (u16*)(ws + 33554432);          // R2: T x D
    u16*   zb     = (u16*)(ws + 50331648);          // R3: T x D
    u16*   dtb    = (u16*)(ws + 67108864);          // R4: T x D
    u16*   dotsb  = (u16*)(ws + 83886080);          // R5: T x 32

    // 1. fused W_in cast + LN(x)
    castln_kernel<<<12288, 256, 0, stream>>>(W_in, wb_in, x, ln_g, ln_b, xnb);
    // 2. xz = xn @ W_in^T + b_in -> xsb | zb   (256^2 8-phase, 256 blocks)
    gemm256<0><<<dim3(16, 16), 512, 0, stream>>>(xnb, wb_in, b_in, nullptr,
                                                 xsb, zb, 2048);
    // 3. cast W_dt -> wb_dt rows 0..2047, W_B -> 2048..2063, W_C -> 2064..2079,
    //    W_out -> wb_out (R0). Rows 2080..2303 uninit; those cols discarded.
    cast4_kernel<<<8256, 256, 0, stream>>>(
        W_dt, wb_dt, 1048576,
        W_B,  wb_dt + (size_t)2048 * 2048, 8192,
        W_C,  wb_dt + (size_t)2064 * 2048, 8192,
        W_out, wb_out, 1048576);
    // 4. dt GEMM + BC dots: N padded to 2304 (9 tiles), 144 blocks
    gemm256<1><<<dim3(16, 9), 512, 0, stream>>>(xsb, wb_dt, b_dt, nullptr,
                                                dtb, dotsb, 2048);
    // 5. fused P + SSM + gate (gated overwrites R1; wb_dt dead)
    ssm_gate_kernel<<<T_TOK, 256, 0, stream>>>(dtb, xsb, zb, stateA, dotsb,
                                               b_B, b_C, gated);
    // 6. out = gated @ W_out^T + b_out + x, 128 blocks
    gemm256<2><<<dim3(16, 8), 512, 0, stream>>>(gated, wb_out, b_out, x,
                                                (float*)d_out, nullptr, 2048);
}

// Round 7
// 355.442 us; speedup vs baseline: 1.1509x; 1.1218x over previous
//
#include <hip/hip_runtime.h>

typedef unsigned short u16;
typedef float f32x4 __attribute__((ext_vector_type(4)));
typedef __bf16 bf16x8 __attribute__((ext_vector_type(8)));

// ---------- bf16 helpers (RNE) ----------
__device__ __forceinline__ u16 f2bf(float f) {
    unsigned u = __float_as_uint(f);
    u += 0x7FFFu + ((u >> 16) & 1u);
    return (u16)(u >> 16);
}
__device__ __forceinline__ float b2f(u16 h) {
    return __uint_as_float(((unsigned)h) << 16);
}

// ---------- async global->LDS, 16B per lane, wave-uniform LDS base ----------
__device__ __forceinline__ void async16(const u16* g, u16* l) {
    __builtin_amdgcn_global_load_lds(
        (__attribute__((address_space(1))) void*)(u16*)g,
        (__attribute__((address_space(3))) void*)l,
        16, 0, 0);
}

#define T_TOK 4096
#define DIM   2048

// ---------- fused: W_in cast (blocks 0..8191) + LayerNorm (blocks 8192..12287) ----------
__global__ __launch_bounds__(256) void castln_kernel(const float* __restrict__ W_in,
                                                     u16* __restrict__ wb_in,
                                                     const float* __restrict__ x,
                                                     const float* __restrict__ g,
                                                     const float* __restrict__ b,
                                                     u16* __restrict__ o) {
    __shared__ float s1[4], s2[4];
    int blk = blockIdx.x, tid = threadIdx.x;
    if (blk < 8192) {               // cast path: 2,097,152 float4s
        int i = blk * 256 + tid;
        float4 f = ((const float4*)W_in)[i];
        ushort4 u;
        u.x = f2bf(f.x); u.y = f2bf(f.y); u.z = f2bf(f.z); u.w = f2bf(f.w);
        ((ushort4*)wb_in)[i] = u;
        return;
    }
    int t = blk - 8192;
    int wave = tid >> 6, lane = tid & 63;
    size_t base = (size_t)t * DIM;
    int d0 = tid * 8;
    float4 v0 = *(const float4*)(x + base + d0);
    float4 v1 = *(const float4*)(x + base + d0 + 4);
    float v[8] = {v0.x, v0.y, v0.z, v0.w, v1.x, v1.y, v1.z, v1.w};
    float s = 0.f;
#pragma unroll
    for (int j = 0; j < 8; ++j) s += v[j];
#pragma unroll
    for (int o2 = 32; o2; o2 >>= 1) s += __shfl_xor(s, o2);
    if (lane == 0) s1[wave] = s;
    __syncthreads();
    float mu = (s1[0] + s1[1] + s1[2] + s1[3]) * (1.f / DIM);
    float q = 0.f;
#pragma unroll
    for (int j = 0; j < 8; ++j) { float dd = v[j] - mu; q += dd * dd; }
#pragma unroll
    for (int o2 = 32; o2; o2 >>= 1) q += __shfl_xor(q, o2);
    if (lane == 0) s2[wave] = q;
    __syncthreads();
    float var = (s2[0] + s2[1] + s2[2] + s2[3]) * (1.f / DIM);
    float rs = rsqrtf(var + 1e-5f);
    float4 g0 = *(const float4*)(g + d0), g1 = *(const float4*)(g + d0 + 4);
    float4 b0 = *(const float4*)(b + d0), b1 = *(const float4*)(b + d0 + 4);
    float gv[8] = {g0.x, g0.y, g0.z, g0.w, g1.x, g1.y, g1.z, g1.w};
    float bv[8] = {b0.x, b0.y, b0.z, b0.w, b1.x, b1.y, b1.z, b1.w};
    ushort4 r0, r1;
    u16* rp0 = (u16*)&r0; u16* rp1 = (u16*)&r1;
#pragma unroll
    for (int j = 0; j < 4; ++j) {
        rp0[j] = f2bf((v[j] - mu) * rs * gv[j] + bv[j]);
        rp1[j] = f2bf((v[j + 4] - mu) * rs * gv[j + 4] + bv[j + 4]);
    }
    *(ushort4*)(o + base + d0) = r0;
    *(ushort4*)(o + base + d0 + 4) = r1;
}

// ---------- 4-range weight cast (W_dt, W_B, W_C, W_out in one launch) ----------
__global__ __launch_bounds__(256) void cast4_kernel(const float* __restrict__ s0, u16* __restrict__ d0, int n0,
                                                    const float* __restrict__ s1, u16* __restrict__ d1, int n1,
                                                    const float* __restrict__ s2, u16* __restrict__ d2, int n2,
                                                    const float* __restrict__ s3, u16* __restrict__ d3, int n3) {
    int j = blockIdx.x * 256 + threadIdx.x;
    const float* s; u16* d;
    if (j < n0) { s = s0; d = d0; }
    else {
        j -= n0;
        if (j < n1) { s = s1; d = d1; }
        else {
            j -= n1;
            if (j < n2) { s = s2; d = d2; }
            else { j -= n2; if (j >= n3) return; s = s3; d = d3; }
        }
    }
    float4 f = ((const float4*)s)[j];
    ushort4 u;
    u.x = f2bf(f.x); u.y = f2bf(f.y); u.z = f2bf(f.z); u.w = f2bf(f.w);
    ((ushort4*)d)[j] = u;
}

// ---------- wide GEMM: 256x256 8-phase, one barrier/phase (round-6 best) ----------
// Frozen at round-6 config: 77.4us, MfmaUtil ~20, 0 bank conflicts. Phase:
//   ds_reads; stage(2 gload_lds); setprio1; 16 MFMA; setprio0; [vmcnt(2)];
//   s_barrier
// Stage schedule per iter i (buf0=tile 2i read p0-3, buf1=2i+1 read p4-7):
//   p0: A-h1->buf1@k1   p1: B-h0->buf1@k1   p2: B-h1->buf1@k1
//   p3: A-h0->buf0@kn  +vmcnt(2)            p4: A-h1->buf0@kn
//   p5: B-h0->buf0@kn   p6: B-h1->buf0@kn   p7: A-h0->buf1@kn1 +vmcnt(2)
// Epilogue: split cols<2048 -> Xs (bf16), >=2048 -> Z (bf16).
#define GBM 256
#define GBN 256
#define GBK 64

#define WAITV2 asm volatile("s_waitcnt vmcnt(2)" ::: "memory")

__global__ __launch_bounds__(512) void gemm_wide(const u16* __restrict__ A,
                                                 const u16* __restrict__ W,
                                                 const float* __restrict__ bias,
                                                 u16* __restrict__ Xs,
                                                 u16* __restrict__ Z, int K) {
    __shared__ __align__(16) u16 lA[2][GBM * GBK];   // 64 KB
    __shared__ __align__(16) u16 lB[2][GBN * GBK];   // 64 KB
    const int tid = threadIdx.x;
    const int wv = tid >> 6, lane = tid & 63;
    const int quad = lane >> 4, l16 = lane & 15;
    const int wr = wv >> 2, wc = wv & 3;               // 2 x 4 wave grid
    const int tM = blockIdx.x * GBM, tN = blockIdx.y * GBN;

    const int srow = tid >> 3;                          // 0..63
    const int swz = ((tid & 7) ^ (srow & 7)) * 8;       // pre-swizzled src chunk
    const u16* gA = A + (size_t)(tM + srow) * 2048 + swz;
    const u16* gW = W + (size_t)(tN + srow) * 2048 + swz;

#define STAGE_AH(BI, KC, H) do {                                              \
    _Pragma("unroll") for (int r_ = 2 * (H); r_ < 2 * (H) + 2; ++r_)          \
      async16(gA + (size_t)r_ * 64 * 2048 + (KC),                             \
              &lA[BI][(r_ * 64 + wv * 8) * GBK]);                             \
  } while (0)
#define STAGE_BH(BI, KC, H) do {                                              \
    _Pragma("unroll") for (int r_ = 2 * (H); r_ < 2 * (H) + 2; ++r_)          \
      async16(gW + (size_t)r_ * 64 * 2048 + (KC),                             \
              &lB[BI][(r_ * 64 + wv * 8) * GBK]);                             \
  } while (0)

    int aoff[2][4][2], boff[2][2][2];
#pragma unroll
    for (int qm = 0; qm < 2; ++qm)
#pragma unroll
        for (int mi = 0; mi < 4; ++mi)
#pragma unroll
            for (int h = 0; h < 2; ++h) {
                int row = wr * 128 + (qm * 4 + mi) * 16 + l16;
                aoff[qm][mi][h] = row * GBK + (((h * 4 + quad) ^ (l16 & 7)) * 8);
            }
#pragma unroll
    for (int qn = 0; qn < 2; ++qn)
#pragma unroll
        for (int ni = 0; ni < 2; ++ni)
#pragma unroll
            for (int h = 0; h < 2; ++h) {
                int row = wc * 64 + (qn * 2 + ni) * 16 + l16;
                boff[qn][ni][h] = row * GBK + (((h * 4 + quad) ^ (l16 & 7)) * 8);
            }

    f32x4 acc[8][4] = {};
    bf16x8 af[4][2];   // A frags persist across the two phases of a qm-half

#define PHASE(BI, QM, QN, LOADA, STAGE_STMT, WAIT_STMT) do {                  \
    if (LOADA) {                                                              \
      _Pragma("unroll") for (int mi_ = 0; mi_ < 4; ++mi_)                     \
        _Pragma("unroll") for (int h_ = 0; h_ < 2; ++h_)                      \
          af[mi_][h_] = *(const bf16x8*)&lA[BI][aoff[QM][mi_][h_]];           \
    }                                                                         \
    bf16x8 bfr_[2][2];                                                        \
    _Pragma("unroll") for (int ni_ = 0; ni_ < 2; ++ni_)                       \
      _Pragma("unroll") for (int h_ = 0; h_ < 2; ++h_)                        \
        bfr_[ni_][h_] = *(const bf16x8*)&lB[BI][boff[QN][ni_][h_]];           \
    STAGE_STMT;                                                               \
    __builtin_amdgcn_s_setprio(1);                                            \
    _Pragma("unroll") for (int mi_ = 0; mi_ < 4; ++mi_)                       \
      _Pragma("unroll") for (int ni_ = 0; ni_ < 2; ++ni_)                     \
        _Pragma("unroll") for (int h_ = 0; h_ < 2; ++h_)                      \
          acc[QM * 4 + mi_][QN * 2 + ni_] =                                   \
              __builtin_amdgcn_mfma_f32_16x16x32_bf16(                        \
                  af[mi_][h_], bfr_[ni_][h_],                                 \
                  acc[QM * 4 + mi_][QN * 2 + ni_], 0, 0, 0);                  \
    __builtin_amdgcn_s_setprio(0);                                            \
    WAIT_STMT;                                                                \
    __builtin_amdgcn_s_barrier();                                             \
  } while (0)

    STAGE_AH(0, 0, 0);
    STAGE_AH(0, 0, 1);
    STAGE_BH(0, 0, 0);
    STAGE_BH(0, 0, 1);
    STAGE_AH(1, 64, 0);
    WAITV2;
    __builtin_amdgcn_s_barrier();

    const int NIT = K >> 7;                 // 2 K-tiles per iteration
    for (int it = 0; it < NIT; ++it) {
        const int k1 = it * 128 + 64;
        int kn = it * 128 + 128;
        if (kn > K - 64) kn = K - 64;
        int kn1 = it * 128 + 192;
        if (kn1 > K - 64) kn1 = K - 64;

        PHASE(0, 0, 0, 1, STAGE_AH(1, k1, 1),  (void)0);   // p0
        PHASE(0, 0, 1, 0, STAGE_BH(1, k1, 0),  (void)0);   // p1
        PHASE(0, 1, 0, 1, STAGE_BH(1, k1, 1),  (void)0);   // p2
        PHASE(0, 1, 1, 0, STAGE_AH(0, kn, 0),  WAITV2);    // p3
        PHASE(1, 0, 0, 1, STAGE_AH(0, kn, 1),  (void)0);   // p4
        PHASE(1, 0, 1, 0, STAGE_BH(0, kn, 0),  (void)0);   // p5
        PHASE(1, 1, 0, 1, STAGE_BH(0, kn, 1),  (void)0);   // p6
        PHASE(1, 1, 1, 0, STAGE_AH(1, kn1, 0), WAITV2);    // p7
    }

    asm volatile("s_waitcnt vmcnt(0)" ::: "memory");

    const bool isb_z = (tN >= 2048);
    u16* dst = isb_z ? Z : Xs;
#pragma unroll
    for (int mi = 0; mi < 8; ++mi) {
#pragma unroll
        for (int ni = 0; ni < 4; ++ni) {
            int col = tN + wc * 64 + ni * 16 + l16;
            float bv = bias[col];
            int ocol = isb_z ? (col - 2048) : col;
#pragma unroll
            for (int r = 0; r < 4; ++r) {
                int row = tM + wr * 128 + mi * 16 + quad * 4 + r;
                dst[(size_t)row * 2048 + ocol] = f2bf(acc[mi][ni][r] + bv);
            }
        }
    }
#undef PHASE
#undef STAGE_AH
#undef STAGE_BH
}

// ---------- narrow GEMM: BM=128, BN=64, BK=64, XOR-swizzled (round-1 form) ----------
// Reverted to round-1 measured config (wall-clock better than the 256^2 port
// for these shapes: 1056/1024 blocks pack the device tail better).
// EPI 1 = dt: col<2048 -> min(softplus(v),1) bf16 (cheap form); 2048<=col<2080
//         -> raw dots bf16. EPI 2 = out: fp32 v + resid.
#define NBM 128
#define NBN 64
#define NBK 64

template <int EPI>
__global__ __launch_bounds__(256) void gemm_nw(const u16* __restrict__ A, int lda,
                                               const u16* __restrict__ W, int ldw,
                                               const float* __restrict__ bias,
                                               const float* __restrict__ resid,
                                               void* __restrict__ C, int ldc, int K,
                                               u16* __restrict__ dots) {
    __shared__ __align__(16) u16 lAB[(NBM + NBN) * NBK];  // 24 KB
    const int tid = threadIdx.x;
    const int wave = tid >> 6, lane = tid & 63;
    const int quad = lane >> 4, l16 = lane & 15;
    const int tM = blockIdx.x * NBM;
    const int tN = blockIdx.y * NBN;
    const int wr = wave >> 1, wc = wave & 1;

    const int rowin = tid >> 3;                    // 0..31
    const int r3 = rowin & 7;                      // swizzle key
    const int col8 = ((tid & 7) ^ r3) * 8;
    const u16* gptr[6];
    u16* ldst[6];
#pragma unroll
    for (int i = 0; i < 6; ++i) {
        int trow = i * 32 + rowin;
        const u16* src = (i < 4) ? (A + (size_t)(tM + trow) * lda)
                                 : (W + (size_t)(tN + (trow - NBM)) * ldw);
        gptr[i] = src + col8;
        ldst[i] = &lAB[(i * 32 + wave * 8) * NBK];
    }

    int a_off[2][4], b_off[2][2];
#pragma unroll
    for (int h = 0; h < 2; ++h) {
#pragma unroll
        for (int mi = 0; mi < 4; ++mi)
            a_off[h][mi] = (wr * 64 + mi * 16 + l16) * NBK +
                           (((h * 4 + quad) ^ (l16 & 7)) * 8);
#pragma unroll
        for (int ni = 0; ni < 2; ++ni)
            b_off[h][ni] = (NBM + wc * 32 + ni * 16 + l16) * NBK +
                           (((h * 4 + quad) ^ (l16 & 7)) * 8);
    }

    f32x4 acc[4][2] = {};

    for (int kt = 0; kt < K; kt += NBK) {
#pragma unroll
        for (int i = 0; i < 6; ++i) async16(gptr[i] + kt, ldst[i]);
        __syncthreads();
        bf16x8 af[2][4], bfr[2][2];
#pragma unroll
        for (int h = 0; h < 2; ++h) {
#pragma unroll
            for (int mi = 0; mi < 4; ++mi) af[h][mi] = *(const bf16x8*)&lAB[a_off[h][mi]];
#pragma unroll
            for (int ni = 0; ni < 2; ++ni) bfr[h][ni] = *(const bf16x8*)&lAB[b_off[h][ni]];
        }
#pragma unroll
        for (int h = 0; h < 2; ++h)
#pragma unroll
            for (int mi = 0; mi < 4; ++mi)
#pragma unroll
                for (int ni = 0; ni < 2; ++ni)
                    acc[mi][ni] = __builtin_amdgcn_mfma_f32_16x16x32_bf16(
                        af[h][mi], bfr[h][ni], acc[mi][ni], 0, 0, 0);
        __syncthreads();
    }

#pragma unroll
    for (int mi = 0; mi < 4; ++mi) {
#pragma unroll
        for (int ni = 0; ni < 2; ++ni) {
            int col = tN + wc * 32 + ni * 16 + l16;
            float bv = (EPI == 1 && col >= 2048) ? 0.f : bias[col];
#pragma unroll
            for (int r = 0; r < 4; ++r) {
                int row = tM + wr * 64 + mi * 16 + quad * 4 + r;
                float v = acc[mi][ni][r] + bv;
                if constexpr (EPI == 1) {
                    if (col < 2048) {
                        // min(softplus(v),1): v > ln(e-1) -> 1
                        float sp = (v > 0.5413f) ? 1.0f
                                                 : __logf(1.0f + __expf(v));
                        ((u16*)C)[(size_t)row * ldc + col] = f2bf(sp);
                    } else if (col < 2080) {
                        dots[(size_t)row * 32 + (col - 2048)] = f2bf(v);
                    }
                } else {
                    size_t idx = (size_t)row * ldc + col;
                    ((float*)C)[idx] = v + resid[idx];
                }
            }
        }
    }
}

// ---------- fused P + SSM + gate v2: A in registers, 8 tokens/block ----------
// Old version re-read the full A matrix (131 KB) from L2 per token: 4096 x
// 131 KB = 537 MB L2 traffic, latency-exposed through 16 serial float4-pair
// rounds/thread. v2: grid 512 blocks x 8 tokens; each thread owns 8 cols
// (d0 = tid*8) and keeps A[n][j] in 128 f32 registers (static indexing, rule
// #20: token loop NOT unrolled -- only LDS Pl[tt] is runtime-indexed).
// A L2 traffic drops 8x (67 MB); dt/xs/z stream coalesced; exp floor ~7us.
__global__ __launch_bounds__(256) void ssm_gate2_kernel(const u16* __restrict__ dtb,
                                                        const u16* __restrict__ xsb,
                                                        const u16* __restrict__ zb,
                                                        const float* __restrict__ A,
                                                        const u16* __restrict__ dots,
                                                        const float* __restrict__ bB,
                                                        const float* __restrict__ bC,
                                                        u16* __restrict__ gated) {
    __shared__ float Pl[8][16];
    const int tid = threadIdx.x;
    const int t0 = blockIdx.x * 8;
    const int d0 = tid * 8;

    float a[16][8];
#pragma unroll
    for (int n = 0; n < 16; ++n) {
        float4 a0 = *(const float4*)(A + n * DIM + d0);
        float4 a1 = *(const float4*)(A + n * DIM + d0 + 4);
        a[n][0] = a0.x; a[n][1] = a0.y; a[n][2] = a0.z; a[n][3] = a0.w;
        a[n][4] = a1.x; a[n][5] = a1.y; a[n][6] = a1.z; a[n][7] = a1.w;
    }
    if (tid < 128) {
        int tt = tid >> 4, n = tid & 15;
        float Bv = b2f(dots[(size_t)(t0 + tt) * 32 + n]) + bB[n];
        float Cv = b2f(dots[(size_t)(t0 + tt) * 32 + 16 + n]) + bC[n];
        Pl[tt][n] = Bv * Cv;
    }
    __syncthreads();

    for (int tt = 0; tt < 8; ++tt) {
        size_t dbase = (size_t)(t0 + tt) * DIM;
        ushort4 dth0 = *(const ushort4*)(dtb + dbase + d0);
        ushort4 dth1 = *(const ushort4*)(dtb + dbase + d0 + 4);
        ushort4 xsh0 = *(const ushort4*)(xsb + dbase + d0);
        ushort4 xsh1 = *(const ushort4*)(xsb + dbase + d0 + 4);
        ushort4 zh0  = *(const ushort4*)(zb + dbase + d0);
        ushort4 zh1  = *(const ushort4*)(zb + dbase + d0 + 4);
        float dtv[8], xsv[8], zv[8];
        const u16* dp0 = (const u16*)&dth0; const u16* dp1 = (const u16*)&dth1;
        const u16* xp0 = (const u16*)&xsh0; const u16* xp1 = (const u16*)&xsh1;
        const u16* zp0 = (const u16*)&zh0;  const u16* zp1 = (const u16*)&zh1;
#pragma unroll
        for (int j = 0; j < 4; ++j) {
            dtv[j] = b2f(dp0[j]); dtv[j + 4] = b2f(dp1[j]);
            xsv[j] = b2f(xp0[j]); xsv[j + 4] = b2f(xp1[j]);
            zv[j]  = b2f(zp0[j]); zv[j + 4]  = b2f(zp1[j]);
        }
        float s[8] = {};
#pragma unroll
        for (int n = 0; n < 16; ++n) {
            float pn = Pl[tt][n];
#pragma unroll
            for (int j = 0; j < 8; ++j) s[j] += pn * __expf(a[n][j] * dtv[j]);
        }
        ushort4 r0, r1;
        u16* rp0 = (u16*)&r0; u16* rp1 = (u16*)&r1;
#pragma unroll
        for (int j = 0; j < 8; ++j) {
            float y = s[j] * xsv[j];
            float sz = zv[j] * (1.0f / (1.0f + __expf(-zv[j])));
            u16 hv = f2bf(y * sz);
            if (j < 4) rp0[j] = hv; else rp1[j - 4] = hv;
        }
        *(ushort4*)(gated + dbase + d0) = r0;
        *(ushort4*)(gated + dbase + d0 + 4) = r1;
    }
}

// ---------- launch ----------
// ws layout (84.15 MB peak):
//   R0 [0, 16.78M):       wb_in bf16 -> after gemm_wide: wb_out bf16 [0, 8.39M)
//   R1 [16.78M, 33.55M):  xnb bf16 -> wb_dt bf16 2112x2048 [16.78M, 25.43M)
//                         -> gated bf16 (after dt gemm, full R1)
//   R2 [33.55M, 50.33M):  xsb bf16 (T x D)
//   R3 [50.33M, 67.11M):  zb  bf16 (T x D)
//   R4 [67.11M, 83.89M):  dtb bf16 (T x D)
//   R5 [83.89M, 84.15M):  dots bf16 (T x 32)
extern "C" void kernel_launch(void* const* d_in, const int* in_sizes, int n_in,
                              void* d_out, int out_size, void* d_ws, size_t ws_size,
                              hipStream_t stream) {
    const float* x      = (const float*)d_in[0];
    const float* ln_g   = (const float*)d_in[1];
    const float* ln_b   = (const float*)d_in[2];
    const float* W_in   = (const float*)d_in[3];
    const float* b_in   = (const float*)d_in[4];
    const float* stateA = (const float*)d_in[5];
    const float* W_B    = (const float*)d_in[6];
    const float* b_B    = (const float*)d_in[7];
    const float* W_C    = (const float*)d_in[8];
    const float* b_C    = (const float*)d_in[9];
    const float* W_dt   = (const float*)d_in[10];
    const float* b_dt   = (const float*)d_in[11];
    const float* W_out  = (const float*)d_in[12];
    const float* b_out  = (const float*)d_in[13];

    char* ws = (char*)d_ws;
    u16*   wb_in  = (u16*)(ws);                     // R0
    u16*   wb_out = (u16*)(ws);                     // R0 reuse (8.4 MB)
    u16*   xnb    = (u16*)(ws + 16777216);          // R1
    u16*   wb_dt  = (u16*)(ws + 16777216);          // R1 reuse: 2112 x 2048
    u16*   gated  = (u16*)(ws + 16777216);          // R1 reuse: T x D
    u16*   xsb    = (u16*)(ws + 33554432);          // R2: T x D
    u16*   zb     = (u16*)(ws + 50331648);          // R3: T x D
    u16*   dtb    = (u16*)(ws + 67108864);          // R4: T x D
    u16*   dotsb  = (u16*)(ws + 83886080);          // R5: T x 32

    // 1. fused W_in cast + LN(x)
    castln_kernel<<<12288, 256, 0, stream>>>(W_in, wb_in, x, ln_g, ln_b, xnb);
    // 2. xz = xn @ W_in^T + b_in -> xsb | zb   (256^2 8-phase, 256 blocks)
    gemm_wide<<<dim3(16, 16), 512, 0, stream>>>(xnb, wb_in, b_in, xsb, zb, 2048);
    // 3. cast W_dt -> wb_dt rows 0..2047, W_B -> 2048..2063, W_C -> 2064..2079,
    //    W_out -> wb_out (R0). Pad rows 2080..2111 hold poison; outputs discarded.
    cast4_kernel<<<8256, 256, 0, stream>>>(
        W_dt, wb_dt, 1048576,
        W_B,  wb_dt + (size_t)2048 * 2048, 8192,
        W_C,  wb_dt + (size_t)2064 * 2048, 8192,
        W_out, wb_out, 1048576);
    // 4. dt GEMM + BC dots: narrow tiles, N = 2112 (33 tiles), 1056 blocks
    gemm_nw<1><<<dim3(32, 33), 256, 0, stream>>>(xsb, 2048, wb_dt, 2048, b_dt,
                                                 nullptr, dtb, 2048, 2048, dotsb);
    // 5. fused P + SSM + gate v2 (A in registers, 8 tokens/block)
    ssm_gate2_kernel<<<512, 256, 0, stream>>>(dtb, xsb, zb, stateA, dotsb,
                                              b_B, b_C, gated);
    // 6. out = gated @ W_out^T + b_out + x, narrow tiles, 1024 blocks
    gemm_nw<2><<<dim3(32, 32), 256, 0, stream>>>(gated, 2048, wb_out, 2048, b_out,
                                                 x, (float*)d_out, 2048, 2048, nullptr);
}